// Round 7
// baseline (490.593 us; speedup 1.0000x reference)
//
#include <hip/hip_runtime.h>

#define N_NODES    100000
#define N_EDGES    1600000
#define DIM        128
#define OUT_CH     10
#define NUM_GRAPHS 128
#define BN_EPS     1e-5f

#define BSHIFT   8
#define NB2      391
#define CAP2     5120
#define NTILES   782
#define GEMM_GRID 256

// sharded aggregation: 8 channel-shards, shard-major X layout.
#define AGG_BLOCKS  2048
#define AGG_RANKS   (AGG_BLOCKS / 8)                          // 256 per shard
#define AGG_NPR     ((N_NODES + AGG_RANKS - 1) / AGG_RANKS)   // 391 nodes/rank

typedef __attribute__((ext_vector_type(8))) short short8;
typedef __attribute__((ext_vector_type(4))) float floatx4;
typedef __attribute__((ext_vector_type(2))) float f32x2;
typedef __attribute__((ext_vector_type(4))) unsigned uint4v;

__device__ inline float bf2f(unsigned short u) {
    union { unsigned i; float f; } v; v.i = (unsigned)u << 16; return v.f;
}
__device__ inline unsigned short f2bf(float f) {
    union { float f; unsigned i; } v; v.f = f;
    return (unsigned short)((v.i + 0x8000u) >> 16);   // round-half-up, 2 ops
}
__device__ inline float blo(unsigned u) {
    union { unsigned i; float f; } v; v.i = u << 16; return v.f;
}
__device__ inline float bhi(unsigned u) {
    union { unsigned i; float f; } v; v.i = u & 0xFFFF0000u; return v.f;
}

__device__ inline void async_cp16(const unsigned short* g, unsigned short* l) {
    __builtin_amdgcn_global_load_lds(
        (const __attribute__((address_space(1))) void*)g,
        (__attribute__((address_space(3))) void*)l, 16, 0, 0);
}

// ============== cvt x -> bf16 (SHARD-MAJOR), plus workspace zeroing ==============
// xb layout: [shard(8)][node][16 ch] bf16 — each shard slice is a contiguous 3.2 MB
__global__ void k_cvt_x(const float* __restrict__ x, unsigned short* __restrict__ xb,
                        int* __restrict__ gcur, float* __restrict__ stats4,
                        float* __restrict__ pooled) {
    int t = threadIdx.x;
    if (blockIdx.x == 0) {
        for (int i = t; i < NB2 + 1; i += 256) gcur[i] = 0;
        for (int i = t; i < 4 * DIM; i += 256) stats4[i] = 0.f;
        for (int i = t; i < NUM_GRAPHS * DIM; i += 256) pooled[i] = 0.f;
    }
    int idx = blockIdx.x * 256 + t;
    float4 v = ((const float4*)x)[idx];
    ushort4 o;
    o.x = f2bf(v.x); o.y = f2bf(v.y); o.z = f2bf(v.z); o.w = f2bf(v.w);
    int node = idx >> 5, qd = idx & 31;
    int sh = qd >> 2, cc = qd & 3;
    ((ushort4*)xb)[(size_t)sh * (N_NODES * 4) + (size_t)node * 4 + cc] = o;
}

__global__ void k_prep_w(const float* __restrict__ W0, const float* __restrict__ W1,
                         const float* __restrict__ W2, const float* __restrict__ W3,
                         unsigned short* __restrict__ Wt) {
    const float* Ws[4] = {W0, W1, W2, W3};
    const float* W = Ws[blockIdx.y];
    unsigned short* o = Wt + blockIdx.y * (DIM * DIM);
    int idx = blockIdx.x * 256 + threadIdx.x;
    int n = idx >> 7, k = idx & 127;
    o[idx] = f2bf(W[k * DIM + n]);
}

// ===================== bucket partition, LDS-staged =====================
__global__ __launch_bounds__(256)
void k_bucket(const int* __restrict__ src, const int* __restrict__ dst,
              int* __restrict__ gcur, unsigned* __restrict__ pairs) {
    __shared__ int cnt[NB2 + 1];
    __shared__ int lofs[NB2 + 1];
    __shared__ int gbase[NB2 + 1];
    __shared__ int scanA[256], scanB[256];
    __shared__ int stage[8192];

    int t = threadIdx.x;
    for (int i = t; i < NB2 + 1; i += 256) cnt[i] = 0;
    __syncthreads();
    int base = blockIdx.x * 8192;
    int n_e = min(8192, N_EDGES - base);
    for (int i = t; i < n_e; i += 256)
        atomicAdd(&cnt[dst[base + i] >> BSHIFT], 1);
    __syncthreads();
    int vA = cnt[t];
    int vB = (t < NB2 - 256) ? cnt[256 + t] : 0;
    scanA[t] = vA; scanB[t] = vB;
    __syncthreads();
    for (int off = 1; off < 256; off <<= 1) {
        int tA = (t >= off) ? scanA[t - off] : 0;
        int tB = (t >= off) ? scanB[t - off] : 0;
        __syncthreads();
        scanA[t] += tA; scanB[t] += tB;
        __syncthreads();
    }
    lofs[t] = scanA[t] - vA;
    if (t < NB2 - 256) lofs[256 + t] = scanA[255] + scanB[t] - vB;
    __syncthreads();
    for (int i = t; i < NB2; i += 256) {
        gbase[i] = (cnt[i] > 0) ? atomicAdd(&gcur[i], cnt[i]) : 0;
        cnt[i] = lofs[i];
    }
    __syncthreads();
    for (int i = t; i < n_e; i += 256) {
        int d = dst[base + i];
        int b = d >> BSHIFT;
        int pos = atomicAdd(&cnt[b], 1);
        stage[pos] = (int)(((unsigned)src[base + i] << 8) | (unsigned)(d & 255));
    }
    __syncthreads();
    int w = t >> 6, lane = t & 63;
    for (int b = w; b < NB2; b += 4) {
        int len = cnt[b] - lofs[b];
        int g0  = gbase[b];
        int maxlen = CAP2 - g0; if (maxlen < 0) maxlen = 0;
        if (len > maxlen) len = maxlen;
        unsigned* dp = pairs + (size_t)b * CAP2 + g0;
        const int* sp = stage + lofs[b];
        for (int i = lane; i < len; i += 64) dp[i] = (unsigned)sp[i];
    }
}

__global__ void k_bscan(const int* __restrict__ gcur, int* __restrict__ bbase,
                        int* __restrict__ row_ptr) {
    __shared__ int sh[512];
    int t = threadIdx.x;
    int v = (t < NB2) ? min(gcur[t], CAP2) : 0;
    sh[t] = v; __syncthreads();
    for (int off = 1; off < 512; off <<= 1) {
        int tmp = (t >= off) ? sh[t - off] : 0;
        __syncthreads();
        sh[t] += tmp;
        __syncthreads();
    }
    if (t < NB2) bbase[t] = sh[t] - v;
    if (t == NB2 - 1) { bbase[NB2] = sh[t]; row_ptr[N_NODES] = sh[t]; }
}

// col entries are PRE-SCALED byte offsets (src_node << 5 = offset of the 32 B
// shard-row) so k_agg's gather is SGPR-base + 32-bit-voffset with minimal
// per-lane address arithmetic.
__global__ __launch_bounds__(256)
void k_csr(const unsigned* __restrict__ pairs, const int* __restrict__ gcur,
           const int* __restrict__ bbase, int* __restrict__ row_ptr,
           int* __restrict__ col) {
    __shared__ int hist[256];
    __shared__ int cur[256];
    __shared__ int stage[CAP2];
    int bi = blockIdx.x, t = threadIdx.x;
    hist[t] = 0; __syncthreads();
    int n = min(gcur[bi], CAP2);
    const unsigned* P = pairs + (size_t)bi * CAP2;
    for (int i = t; i < n; i += 256)
        atomicAdd(&hist[P[i] & 255u], 1);
    __syncthreads();
    int self = hist[t];
    cur[t] = self; __syncthreads();
    for (int off = 1; off < 256; off <<= 1) {
        int tmp = (t >= off) ? cur[t - off] : 0;
        __syncthreads();
        cur[t] += tmp;
        __syncthreads();
    }
    int excl = cur[t] - self;
    int base = bbase[bi];
    int node = (bi << 8) + t;
    if (node < N_NODES) row_ptr[node] = base + excl;
    cur[t] = excl;
    __syncthreads();
    for (int i = t; i < n; i += 256) {
        unsigned e = P[i];
        int pos = atomicAdd(&cur[e & 255u], 1);
        stage[pos] = (int)((e >> 8) << 5);   // byte offset of 32 B shard-row
    }
    __syncthreads();
    for (int i = t; i < n; i += 256) col[base + i] = stage[i];
}

// ============================ Aggregation ============================
// Xs SHARD-MAJOR [shard][node][16ch] bf16, 3.2 MB/shard = L2-resident
// (FETCH 47 MB). Static partition: shard=blockIdx&7, rank=blockIdx>>3.
// Round-7 VALU diet (round-6 was issue-bound, 51% busy, ~56M wave-insts):
//  - wave = 8 node-slots x 4 edge-slots x 2 ch-lanes; stride-4 per-lane
//    loop with NATURAL exec-mask predication (no batch-2, no min, no
//    mask fmas) -> slot waste 40%->~20%, mask insts -> 0
//  - f32x2 paired accumulate: lo=u<<16, hi=u&0xFFFF0000, one v_pk_add_f32
//    per 2 values (1.5 inst/value vs 2)
//  - reduce depth 2 (masks 2,4) instead of 3 -> 3 insts/node
//  - 20 VGPR, 0 LDS, 2048x4 waves = exactly full chip for TLP latency hiding
__global__ __launch_bounds__(256)
void k_agg(const unsigned short* __restrict__ Xs,
           unsigned short* __restrict__ Out,
           const int* __restrict__ row_ptr, const int* __restrict__ col) {
    int t = threadIdx.x;
    int w = t >> 6, lane = t & 63;
    int ns = lane >> 3;          // node sub-slot 0..7
    int e  = (lane >> 1) & 3;    // edge slot 0..3
    int ch16 = (lane & 1) << 4;  // which 16 B half of the 32 B shard row
    int shard = blockIdx.x & 7;
    int rank  = blockIdx.x >> 3;
    const char* Xb = (const char*)Xs + (size_t)shard * (N_NODES * 32);
    char* OutB = (char*)Out;

    int n0 = rank * AGG_NPR;
    int n1 = min(n0 + AGG_NPR, N_NODES);
    // each pass: block covers 32 nodes (4 waves x 8 node-slots)
    for (int n = n0 + w * 8 + ns; n < n1; n += 32) {
        int s  = row_ptr[n];
        int en = row_ptr[n + 1];
        f32x2 a0 = {0.f, 0.f}, a1 = {0.f, 0.f}, a2 = {0.f, 0.f}, a3 = {0.f, 0.f};
        for (int p = s + e; p < en; p += 4) {
            int off = col[p] + ch16;
            uint4v x = *(const uint4v*)(Xb + off);
            a0 += (f32x2){blo(x[0]), bhi(x[0])};
            a1 += (f32x2){blo(x[1]), bhi(x[1])};
            a2 += (f32x2){blo(x[2]), bhi(x[2])};
            a3 += (f32x2){blo(x[3]), bhi(x[3])};
        }
        // reduce over the 4 edge slots (lane bits 1..2)
        #pragma unroll
        for (int msk = 2; msk <= 4; msk <<= 1) {
            a0[0] += __shfl_xor(a0[0], msk); a0[1] += __shfl_xor(a0[1], msk);
            a1[0] += __shfl_xor(a1[0], msk); a1[1] += __shfl_xor(a1[1], msk);
            a2[0] += __shfl_xor(a2[0], msk); a2[1] += __shfl_xor(a2[1], msk);
            a3[0] += __shfl_xor(a3[0], msk); a3[1] += __shfl_xor(a3[1], msk);
        }
        if ((lane & 6) == 0) {   // e == 0; both ch-lanes store their 16 B half
            uint4v sv = *(const uint4v*)(Xb + ((size_t)n << 5) + ch16);  // self
            a0 += (f32x2){blo(sv[0]), bhi(sv[0])};
            a1 += (f32x2){blo(sv[1]), bhi(sv[1])};
            a2 += (f32x2){blo(sv[2]), bhi(sv[2])};
            a3 += (f32x2){blo(sv[3]), bhi(sv[3])};
            uint4v r;
            r[0] = (unsigned)f2bf(a0[0]) | ((unsigned)f2bf(a0[1]) << 16);
            r[1] = (unsigned)f2bf(a1[0]) | ((unsigned)f2bf(a1[1]) << 16);
            r[2] = (unsigned)f2bf(a2[0]) | ((unsigned)f2bf(a2[1]) << 16);
            r[3] = (unsigned)f2bf(a3[0]) | ((unsigned)f2bf(a3[1]) << 16);
            __builtin_nontemporal_store(r,
                (uint4v*)(OutB + (size_t)n * 256 + (shard << 5) + ch16));
        }
    }
}

// ================= Persistent pipelined MFMA GEMM =================
// SHARD_OUT: write C in shard-major [shard][node][16ch] (feeds next k_agg).
template<bool BN_LOAD, bool STATS, bool RELU_ST, bool SHARD_OUT>
__global__ __launch_bounds__(256)
void k_gemm(const unsigned short* __restrict__ In, unsigned short* __restrict__ Out,
            const unsigned short* __restrict__ Wt, const float* __restrict__ bias,
            const float* __restrict__ ssum_in, const float* __restrict__ ssq_in,
            const float* __restrict__ gamma, const float* __restrict__ beta,
            float* __restrict__ ssum_out, float* __restrict__ ssq_out) {
    __shared__ __align__(16) unsigned short sB[128 * 128];   // 32 KB
    __shared__ float ssc[128], ssh[128];
    __shared__ float s_sum[128], s_sq[128];

    int t = threadIdx.x;
    int w = t >> 6, lane = t & 63;
    int m = lane & 15;
    int q = lane >> 4;
    int sw = m & 7;

    #pragma unroll
    for (int u = 0; u < 8; ++u) {
        int i = (w * 8 + u) * 64 + lane;
        int n = i >> 4, p = i & 15;
        async_cp16(Wt + n * 128 + ((p ^ (n & 7)) << 3), sB + (size_t)(w * 8 + u) * 512);
    }
    if (BN_LOAD && t < 128) {
        float mn  = ssum_in[t] * (1.0f / N_NODES);
        float var = ssq_in[t] * (1.0f / N_NODES) - mn * mn;
        float inv = rsqrtf(var + BN_EPS);
        float sc  = gamma[t] * inv;
        ssc[t] = sc; ssh[t] = beta[t] - mn * sc;
    }
    if (STATS && t < 128) { s_sum[t] = 0.f; s_sq[t] = 0.f; }

    int tile = blockIdx.x;
    short8 a0[4], a1[4];
    {
        int rA0 = min(tile * 128 + w * 32 + m,      N_NODES - 1);
        int rA1 = min(tile * 128 + w * 32 + 16 + m, N_NODES - 1);
        #pragma unroll
        for (int kk = 0; kk < 4; ++kk) {
            a0[kk] = *(const short8*)(In + (size_t)rA0 * 128 + kk * 32 + q * 8);
            a1[kk] = *(const short8*)(In + (size_t)rA1 * 128 + kk * 32 + q * 8);
        }
    }
    __syncthreads();

    #pragma unroll 1
    for (; tile < NTILES; ) {
        int next = tile + GEMM_GRID;
        short8 b0[4], b1[4];
        if (next < NTILES) {
            int rN0 = min(next * 128 + w * 32 + m,      N_NODES - 1);
            int rN1 = min(next * 128 + w * 32 + 16 + m, N_NODES - 1);
            #pragma unroll
            for (int kk = 0; kk < 4; ++kk) {
                b0[kk] = *(const short8*)(In + (size_t)rN0 * 128 + kk * 32 + q * 8);
                b1[kk] = *(const short8*)(In + (size_t)rN1 * 128 + kk * 32 + q * 8);
            }
        }

        if (BN_LOAD) {
            #pragma unroll
            for (int kk = 0; kk < 4; ++kk) {
                int base = kk * 32 + q * 8;
                #pragma unroll
                for (int j = 0; j < 8; ++j) {
                    float scj = ssc[base + j], shj = ssh[base + j];
                    float f0 = fmaxf(bf2f((unsigned short)a0[kk][j]) * scj + shj, 0.f);
                    float f1 = fmaxf(bf2f((unsigned short)a1[kk][j]) * scj + shj, 0.f);
                    a0[kk][j] = (short)f2bf(f0);
                    a1[kk][j] = (short)f2bf(f1);
                }
            }
        }

        floatx4 acc[2][8] = {};
        #pragma unroll
        for (int kk = 0; kk < 4; ++kk) {
            int cp = (kk * 4 + q) ^ sw;
            #pragma unroll
            for (int c = 0; c < 8; ++c) {
                int nr = c * 16 + m;
                short8 b = *(const short8*)&sB[nr * 128 + (cp << 3)];
                acc[0][c] = __builtin_amdgcn_mfma_f32_16x16x32_bf16(b, a0[kk], acc[0][c], 0, 0, 0);
                acc[1][c] = __builtin_amdgcn_mfma_f32_16x16x32_bf16(b, a1[kk], acc[1][c], 0, 0, 0);
            }
        }

        int r0 = tile * 128;
        #pragma unroll
        for (int c = 0; c < 8; ++c) {
            int ch0 = c * 16 + q * 4;
            float4 bv = *(const float4*)(bias + ch0);
            float sr[4] = {0,0,0,0}, qr[4] = {0,0,0,0};
            #pragma unroll
            for (int h = 0; h < 2; ++h) {
                int node = r0 + w * 32 + h * 16 + m;
                float v0 = acc[h][c][0] + bv.x;
                float v1 = acc[h][c][1] + bv.y;
                float v2 = acc[h][c][2] + bv.z;
                float v3 = acc[h][c][3] + bv.w;
                if (RELU_ST) {
                    v0 = fmaxf(v0, 0.f); v1 = fmaxf(v1, 0.f);
                    v2 = fmaxf(v2, 0.f); v3 = fmaxf(v3, 0.f);
                }
                if (node < N_NODES) {
                    ushort4 o;
                    o.x = f2bf(v0); o.y = f2bf(v1); o.z = f2bf(v2); o.w = f2bf(v3);
                    if (SHARD_OUT) {
                        // shard = c, quad within shard = q
                        *(ushort4*)(Out + (size_t)c * (N_NODES * 16) + (size_t)node * 16 + q * 4) = o;
                    } else {
                        *(ushort4*)(Out + (size_t)node * 128 + ch0) = o;
                    }
                    if (STATS) {
                        sr[0] += v0; sr[1] += v1; sr[2] += v2; sr[3] += v3;
                        qr[0] += v0*v0; qr[1] += v1*v1; qr[2] += v2*v2; qr[3] += v3*v3;
                    }
                }
            }
            if (STATS) {
                #pragma unroll
                for (int msk = 1; msk <= 8; msk <<= 1) {
                    #pragma unroll
                    for (int r = 0; r < 4; ++r) {
                        sr[r] += __shfl_xor(sr[r], msk);
                        qr[r] += __shfl_xor(qr[r], msk);
                    }
                }
                if (m == 0) {
                    #pragma unroll
                    for (int r = 0; r < 4; ++r) {
                        atomicAdd(&s_sum[ch0 + r], sr[r]);
                        atomicAdd(&s_sq [ch0 + r], qr[r]);
                    }
                }
            }
        }

        tile = next;
        if (tile < NTILES) {
            #pragma unroll
            for (int kk = 0; kk < 4; ++kk) { a0[kk] = b0[kk]; a1[kk] = b1[kk]; }
        }
    }

    if (STATS) {
        __syncthreads();
        if (t < 128) {
            atomicAdd(&ssum_out[t], s_sum[t]);
            atomicAdd(&ssq_out [t], s_sq[t]);
        }
    }
}

// ============== Pooling (vectorized: thread = channel-quad x subrow) ==============
#define POOL_BLOCKS 782
#define POOL_CHUNK  128
__global__ __launch_bounds__(256)
void k_pool(const unsigned short* __restrict__ h, const int* __restrict__ batch,
            float* __restrict__ pooled) {
    int t  = threadIdx.x;
    int cq = (t & 31) * 4;      // channel quad base
    int r  = t >> 5;            // subrow 0..7
    int n0 = blockIdx.x * POOL_CHUNK;
    if (n0 >= N_NODES) return;
    int n1 = min(n0 + POOL_CHUNK, N_NODES);
    float a0=0.f, a1=0.f, a2=0.f, a3=0.f;
    int g = -1;
    for (int i = n0 + r; i < n1; i += 8) {
        int gi = batch[i];
        if (gi != g) {
            if (g >= 0) {
                atomicAdd(&pooled[g * DIM + cq + 0], a0);
                atomicAdd(&pooled[g * DIM + cq + 1], a1);
                atomicAdd(&pooled[g * DIM + cq + 2], a2);
                atomicAdd(&pooled[g * DIM + cq + 3], a3);
            }
            a0 = a1 = a2 = a3 = 0.f; g = gi;
        }
        ushort4 v = *(const ushort4*)(h + (size_t)i * DIM + cq);
        a0 += bf2f(v.x); a1 += bf2f(v.y); a2 += bf2f(v.z); a3 += bf2f(v.w);
    }
    if (g >= 0) {
        atomicAdd(&pooled[g * DIM + cq + 0], a0);
        atomicAdd(&pooled[g * DIM + cq + 1], a1);
        atomicAdd(&pooled[g * DIM + cq + 2], a2);
        atomicAdd(&pooled[g * DIM + cq + 3], a3);
    }
}

// ============================ Readout (fused) ============================
__global__ void k_readout(const float* __restrict__ pooled,
                          const float* __restrict__ Wl1, const float* __restrict__ bl1,
                          const float* __restrict__ Wl2, const float* __restrict__ bl2,
                          float* __restrict__ out) {
    __shared__ float p[128], r[128];
    int g = blockIdx.x, c = threadIdx.x;
    p[c] = pooled[g * DIM + c];
    __syncthreads();
    float s = bl1[c];
    #pragma unroll 8
    for (int k = 0; k < DIM; ++k) s += p[k] * Wl1[k * DIM + c];
    r[c] = fmaxf(s, 0.f);
    __syncthreads();
    if (c < OUT_CH) {
        float s2 = bl2[c];
        #pragma unroll 8
        for (int k = 0; k < DIM; ++k) s2 += r[k] * Wl2[k * OUT_CH + c];
        out[g * OUT_CH + c] = s2;
    }
}

// ============================ Launch ============================
extern "C" void kernel_launch(void* const* d_in, const int* in_sizes, int n_in,
                              void* d_out, int out_size, void* d_ws, size_t ws_size,
                              hipStream_t stream) {
    const float* x   = (const float*)d_in[0];
    const int*   ei  = (const int*)d_in[1];
    const int*   bat = (const int*)d_in[2];
    const float* W1a = (const float*)d_in[3];
    const float* b1a = (const float*)d_in[4];
    const float* ga  = (const float*)d_in[5];
    const float* ba  = (const float*)d_in[6];
    const float* W2a = (const float*)d_in[7];
    const float* b2a = (const float*)d_in[8];
    const float* W1b = (const float*)d_in[9];
    const float* b1b = (const float*)d_in[10];
    const float* gb  = (const float*)d_in[11];
    const float* bbt = (const float*)d_in[12];
    const float* W2b = (const float*)d_in[13];
    const float* b2b = (const float*)d_in[14];
    const float* Wl1 = (const float*)d_in[15];
    const float* bl1 = (const float*)d_in[16];
    const float* Wl2 = (const float*)d_in[17];
    const float* bl2 = (const float*)d_in[18];
    float* out = (float*)d_out;

    const int* src = ei;
    const int* dst = ei + N_EDGES;

    char* w = (char*)d_ws;
    size_t off = 0;
    auto alloc = [&](size_t bytes) -> char* {
        char* p = w + off; off += (bytes + 255) & ~(size_t)255; return p;
    };
    unsigned short* xb   = (unsigned short*)alloc((size_t)N_NODES * DIM * 2);
    unsigned short* nb0  = (unsigned short*)alloc((size_t)N_NODES * DIM * 2);
    unsigned short* nb1  = (unsigned short*)alloc((size_t)N_NODES * DIM * 2);
    unsigned short* Wtb  = (unsigned short*)alloc((size_t)4 * DIM * DIM * 2);
    unsigned* pairs = (unsigned*)alloc((size_t)NB2 * CAP2 * 4);
    int*   row_ptr = (int*)  alloc((size_t)(N_NODES + 1) * 4);
    int*   col     = (int*)  alloc((size_t)N_EDGES * 4);
    int*   gcur    = (int*)  alloc((NB2 + 1) * 4);
    int*   bbase   = (int*)  alloc((NB2 + 1) * 4);
    float* stats4  = (float*)alloc((size_t)4 * DIM * 4);
    float* pooled  = (float*)alloc((size_t)NUM_GRAPHS * DIM * 4);
    float* ssumA = stats4, *ssqA = stats4 + DIM, *ssumB = stats4 + 2*DIM, *ssqB = stats4 + 3*DIM;

    k_cvt_x<<<(N_NODES * DIM / 4) / 256, 256, 0, stream>>>(x, xb, gcur, stats4, pooled);
    k_prep_w<<<dim3(64, 4), 256, 0, stream>>>(W1a, W2a, W1b, W2b, Wtb);
    const unsigned short* Wt1a = Wtb;
    const unsigned short* Wt2a = Wtb + DIM * DIM;
    const unsigned short* Wt1b = Wtb + 2 * DIM * DIM;
    const unsigned short* Wt2b = Wtb + 3 * DIM * DIM;

    k_bucket<<<(N_EDGES + 8191) / 8192, 256, 0, stream>>>(src, dst, gcur, pairs);
    k_bscan<<<1, 512, 0, stream>>>(gcur, bbase, row_ptr);
    k_csr<<<NB2, 256, 0, stream>>>(pairs, gcur, bbase, row_ptr, col);

    // conv1
    k_agg<<<AGG_BLOCKS, 256, 0, stream>>>(xb, nb0, row_ptr, col);
    k_gemm<false, true, false, false><<<GEMM_GRID, 256, 0, stream>>>(
        nb0, nb1, Wt1a, b1a, nullptr, nullptr, nullptr, nullptr, ssumA, ssqA);
    k_gemm<true, false, true, true><<<GEMM_GRID, 256, 0, stream>>>(
        nb1, nb0, Wt2a, b2a, ssumA, ssqA, ga, ba, nullptr, nullptr);
    // conv2 (nb0 is shard-major here)
    k_agg<<<AGG_BLOCKS, 256, 0, stream>>>(nb0, nb1, row_ptr, col);
    k_gemm<false, true, false, false><<<GEMM_GRID, 256, 0, stream>>>(
        nb1, nb0, Wt1b, b1b, nullptr, nullptr, nullptr, nullptr, ssumB, ssqB);
    k_gemm<true, false, true, false><<<GEMM_GRID, 256, 0, stream>>>(
        nb0, nb1, Wt2b, b2b, ssumB, ssqB, gb, bbt, nullptr, nullptr);
    // readout
    k_pool<<<POOL_BLOCKS, 256, 0, stream>>>(nb1, bat, pooled);
    k_readout<<<NUM_GRAPHS, 128, 0, stream>>>(pooled, Wl1, bl1, Wl2, bl2, out);
}